// Round 5
// baseline (1173.080 us; speedup 1.0000x reference)
//
#include <hip/hip_runtime.h>
#include <hip/hip_bf16.h>
#include <math.h>

// Problem dims (fixed): T=512, B=256, I=128, H=256
#define TT 512
#define BB 256
#define II 128
#define HH 256

typedef float f4 __attribute__((ext_vector_type(4)));

// ---------------------------------------------------------------------------
// Kernel 1: input projection  xi[m][n] = sum_k x[m][k]*Wi[n][k] + bh[n]
//   M = T*B = 131072, K = 128, N = 256. Written into d_out (later overwritten
//   in-place by the recurrence with h_t).
// ---------------------------------------------------------------------------
__global__ __launch_bounds__(256) void proj_kernel(
    const float* __restrict__ x, const float* __restrict__ Wi,
    const float* __restrict__ bh, float* __restrict__ out)
{
    __shared__ float xt[128][68];
    __shared__ float wt[128][64];

    const int tid = threadIdx.x;
    const int m0 = blockIdx.x * 64;
    const int j0 = blockIdx.y * 64;

    {
        const int r  = tid & 63;
        const int kc = tid >> 6;
        const float* xsrc = x  + (size_t)(m0 + r) * II + kc * 32;
        const float* wsrc = Wi + (size_t)(j0 + r) * II + kc * 32;
#pragma unroll
        for (int u = 0; u < 8; ++u) {
            float4 v = *(const float4*)(xsrc + u * 4);
            int k = kc * 32 + u * 4;
            xt[k + 0][r] = v.x; xt[k + 1][r] = v.y;
            xt[k + 2][r] = v.z; xt[k + 3][r] = v.w;
        }
#pragma unroll
        for (int u = 0; u < 8; ++u) {
            float4 v = *(const float4*)(wsrc + u * 4);
            int k = kc * 32 + u * 4;
            wt[k + 0][r] = v.x; wt[k + 1][r] = v.y;
            wt[k + 2][r] = v.z; wt[k + 3][r] = v.w;
        }
    }
    __syncthreads();

    const int ty = tid >> 4, tx = tid & 15;
    const int r0 = ty * 4, c0 = tx * 4;
    float acc[4][4] = {};
#pragma unroll 4
    for (int k = 0; k < 128; ++k) {
        float4 a = *(const float4*)&xt[k][r0];
        float4 b = *(const float4*)&wt[k][c0];
        float av[4] = {a.x, a.y, a.z, a.w};
        float bv[4] = {b.x, b.y, b.z, b.w};
#pragma unroll
        for (int i = 0; i < 4; ++i)
#pragma unroll
            for (int j = 0; j < 4; ++j)
                acc[i][j] += av[i] * bv[j];
    }

    float4 bias = *(const float4*)(bh + j0 + c0);
    float bvv[4] = {bias.x, bias.y, bias.z, bias.w};
#pragma unroll
    for (int i = 0; i < 4; ++i) {
        float4 o;
        o.x = acc[i][0] + bvv[0];
        o.y = acc[i][1] + bvv[1];
        o.z = acc[i][2] + bvv[2];
        o.w = acc[i][3] + bvv[3];
        *(float4*)(out + (size_t)(m0 + r0 + i) * HH + j0 + c0) = o;
    }
}

// ---------------------------------------------------------------------------
// tanh(x) = 1 - 2/(exp(2x)+1). abs err ~1e-6 (validated: absmax unchanged).
// ---------------------------------------------------------------------------
__device__ __forceinline__ float fast_tanh(float x) {
    float e = __expf(2.0f * x);
    return 1.0f - 2.0f * __builtin_amdgcn_rcpf(e + 1.0f);
}

// Opaque (un-rematerializable) 16B global load.
__device__ __forceinline__ f4 ld_f4_opaque(const float* p) {
    f4 r;
    asm volatile("global_load_dwordx4 %0, %1, off"
                 : "=v"(r) : "v"(p));
    return r;
}

// Untracked global store: invisible to the compiler's vmcnt bookkeeping, so
// the s_waitcnt vmcnt(0) it emits before each s_barrier does NOT wait for
// this store's HBM ack (~400-700 cyc). Safe here: no same-step reader of
// the stored address; kernel-end drain guarantees final visibility.
__device__ __forceinline__ void st_f32_untracked(float* p, float v) {
    asm volatile("global_store_dword %0, %1, off" :: "v"(p), "v"(v) : "memory");
}

// ---------------------------------------------------------------------------
// Kernel 2: recurrence. One block per batch row. 1024 threads = 16 waves.
//   Decomposition: wave q -> col-group cg=q>>2 (64 cols), k-group kg=q&3
//   (64 k). Thread = ONE output column (col = cg*64+lane) x 64 k.
//   Fragment: Wh[col][kg*64 .. +64) = 16 f4 = 64 VGPRs (opaque asm loads).
//   hv loads chunked 4-f4-at-a-time with sched_barrier(0) fences: stops the
//   scheduler hoisting all 16 hv loads (that hoist pushed estimated pressure
//   >128 and triggered the AGPR-spill rewrite in rounds 3/4 -> VGPR=48/88).
//   Peak live ~= 64(w)+16(hv)+4(acc)+~20 misc ~= 104 < 128 cap @ 4 waves/EU.
//   Reduce: only 4 partials/col; part[4][256]; all LDS patterns
//   lane-consecutive (conflict-free). tid<256: 4 ds_read + tanh + LDS h
//   write + UNTRACKED global h store (same step, disjoint addresses from
//   the xi loads). Two barriers per step (structural minimum).
// ---------------------------------------------------------------------------
__global__ __launch_bounds__(1024, 4) void rec_kernel(
    const float* __restrict__ Wh, const float* __restrict__ h0,
    float* __restrict__ io)
{
    __shared__ float h[HH];
    __shared__ float part[4][HH];

    const int tid  = threadIdx.x;
    const int b    = blockIdx.x;
    const int lane = tid & 63;
    const int q    = tid >> 6;       // wave id 0..15
    const int cg   = q >> 2;         // col-group 0..3
    const int kg   = q & 3;          // k-group 0..3
    const int col  = cg * 64 + lane; // this thread's output column
    const int kb   = kg * 64;        // k-slice [kb, kb+64)

    // persistent Wh fragment: one column x 64 k = 16 f4 = 64 VGPRs
    f4 w[16];
#pragma unroll
    for (int m = 0; m < 16; ++m)
        w[m] = ld_f4_opaque(Wh + (size_t)col * HH + kb + m * 4);
    asm volatile("s_waitcnt vmcnt(0)" ::: "memory");
    __builtin_amdgcn_sched_barrier(0);   // rule #18

    if (tid < HH) h[tid] = h0[(size_t)b * HH + tid];
    __syncthreads();

    const size_t stride = (size_t)BB * HH;
    size_t ofs = (size_t)b * HH;

#pragma unroll 1
    for (int t = 0; t < TT; ++t) {
        // xi_t (waves 0-3 only; consumed after barrier in reduce phase)
        float xr = 0.0f;
        if (tid < HH) xr = io[ofs + tid];

        // FMA phase: 64 MACs, hv in 4 fenced chunks of 4 f4 (16 floats)
        float a0 = 0.f, a1 = 0.f, a2 = 0.f, a3 = 0.f;
#pragma unroll
        for (int c = 0; c < 4; ++c) {
            const float* hp = &h[kb + c * 16];   // wave-uniform -> broadcast
            f4 h0v = *(const f4*)(hp + 0);
            f4 h1v = *(const f4*)(hp + 4);
            f4 h2v = *(const f4*)(hp + 8);
            f4 h3v = *(const f4*)(hp + 12);
            f4 w0 = w[c * 4 + 0], w1 = w[c * 4 + 1];
            f4 w2 = w[c * 4 + 2], w3 = w[c * 4 + 3];
            a0 += w0.x * h0v.x + w0.y * h0v.y + w0.z * h0v.z + w0.w * h0v.w;
            a1 += w1.x * h1v.x + w1.y * h1v.y + w1.z * h1v.z + w1.w * h1v.w;
            a2 += w2.x * h2v.x + w2.y * h2v.y + w2.z * h2v.z + w2.w * h2v.w;
            a3 += w3.x * h3v.x + w3.y * h3v.y + w3.z * h3v.z + w3.w * h3v.w;
            __builtin_amdgcn_sched_barrier(0);   // bound hv pressure to 16
        }
        // partial for this (col, k-group); lane-consecutive -> conflict-free
        part[kg][col] = (a0 + a1) + (a2 + a3);
        __syncthreads();

        // reduce phase: waves 0-3, one column each
        if (tid < HH) {
            float s = (part[0][tid] + part[1][tid])
                    + (part[2][tid] + part[3][tid]);
            float hn = fast_tanh(xr + s);
            h[tid] = hn;
            st_f32_untracked(io + ofs + tid, hn);  // disjoint from xi reads
        }
        __syncthreads();
        ofs += stride;
    }
}

extern "C" void kernel_launch(void* const* d_in, const int* in_sizes, int n_in,
                              void* d_out, int out_size, void* d_ws, size_t ws_size,
                              hipStream_t stream) {
    const float* x  = (const float*)d_in[0];  // [T,B,I]
    const float* h0 = (const float*)d_in[1];  // [B,H]
    const float* Wi = (const float*)d_in[2];  // [H,I]
    const float* Wh = (const float*)d_in[3];  // [H,H]
    const float* bh = (const float*)d_in[4];  // [H]
    float* out = (float*)d_out;               // [T,B,H]

    dim3 pgrid(TT * BB / 64, HH / 64);
    proj_kernel<<<pgrid, 256, 0, stream>>>(x, Wi, bh, out);
    rec_kernel<<<BB, 1024, 0, stream>>>(Wh, h0, out);
}

// Round 6
// 449.758 us; speedup vs baseline: 2.6082x; 2.6082x over previous
//
#include <hip/hip_runtime.h>
#include <hip/hip_bf16.h>
#include <math.h>

// Problem dims (fixed): T=512, B=256, I=128, H=256
#define TT 512
#define BB 256
#define II 128
#define HH 256

typedef float f4 __attribute__((ext_vector_type(4)));

// ---------------------------------------------------------------------------
// Kernel 1: input projection  xi[m][n] = sum_k x[m][k]*Wi[n][k] + bh[n]
//   M = T*B = 131072, K = 128, N = 256. Written into d_out (later overwritten
//   in-place by the recurrence with h_t).
// ---------------------------------------------------------------------------
__global__ __launch_bounds__(256) void proj_kernel(
    const float* __restrict__ x, const float* __restrict__ Wi,
    const float* __restrict__ bh, float* __restrict__ out)
{
    __shared__ float xt[128][68];
    __shared__ float wt[128][64];

    const int tid = threadIdx.x;
    const int m0 = blockIdx.x * 64;
    const int j0 = blockIdx.y * 64;

    {
        const int r  = tid & 63;
        const int kc = tid >> 6;
        const float* xsrc = x  + (size_t)(m0 + r) * II + kc * 32;
        const float* wsrc = Wi + (size_t)(j0 + r) * II + kc * 32;
#pragma unroll
        for (int u = 0; u < 8; ++u) {
            float4 v = *(const float4*)(xsrc + u * 4);
            int k = kc * 32 + u * 4;
            xt[k + 0][r] = v.x; xt[k + 1][r] = v.y;
            xt[k + 2][r] = v.z; xt[k + 3][r] = v.w;
        }
#pragma unroll
        for (int u = 0; u < 8; ++u) {
            float4 v = *(const float4*)(wsrc + u * 4);
            int k = kc * 32 + u * 4;
            wt[k + 0][r] = v.x; wt[k + 1][r] = v.y;
            wt[k + 2][r] = v.z; wt[k + 3][r] = v.w;
        }
    }
    __syncthreads();

    const int ty = tid >> 4, tx = tid & 15;
    const int r0 = ty * 4, c0 = tx * 4;
    float acc[4][4] = {};
#pragma unroll 4
    for (int k = 0; k < 128; ++k) {
        float4 a = *(const float4*)&xt[k][r0];
        float4 b = *(const float4*)&wt[k][c0];
        float av[4] = {a.x, a.y, a.z, a.w};
        float bv[4] = {b.x, b.y, b.z, b.w};
#pragma unroll
        for (int i = 0; i < 4; ++i)
#pragma unroll
            for (int j = 0; j < 4; ++j)
                acc[i][j] += av[i] * bv[j];
    }

    float4 bias = *(const float4*)(bh + j0 + c0);
    float bvv[4] = {bias.x, bias.y, bias.z, bias.w};
#pragma unroll
    for (int i = 0; i < 4; ++i) {
        float4 o;
        o.x = acc[i][0] + bvv[0];
        o.y = acc[i][1] + bvv[1];
        o.z = acc[i][2] + bvv[2];
        o.w = acc[i][3] + bvv[3];
        *(float4*)(out + (size_t)(m0 + r0 + i) * HH + j0 + c0) = o;
    }
}

// ---------------------------------------------------------------------------
// Kernel 2: recurrence, full inline-asm time loop.
// 512 threads = 8 waves, 1 block per batch row.
//   Wave q = k-group: k in [q*32, q*32+32). Thread: 4 cols = lane*4..+3.
//   Wh fragment: 4 cols x 32 k = 128 floats pinned in v64-v191 (clobbered;
//   compiler CANNOT spill/sink them — r1-r5 showed every C-level pinning
//   attempt gets defeated: VGPR counts 80/84/88/48/64, scratch/AGPR spills).
//   Register map (inside asm):
//     v32-v47  hv prefetch (4 quads, depth-4, counted lgkmcnt(3))
//     v48-v55  4 accumulator pairs (v_pk_fma_f32, packed 2xfp32)
//     v56-v59  part-write staging; v63 xi; v32-v39 reused in reduce
//     v64-v191 Wh fragment (c-major: base 64+32c+4m)
//   Per step: [masked xi load] [8 chunks: wait lgkm(N); 8 pk_fma; prefetch]
//   [merge, ds_write_b128 part] [lgkm(0); barrier] [masked reduce: 8 ds_read,
//   vmcnt(0)+lgkm(0), 7 adds, +xi, tanh via v_exp/v_rcp, ds_write h,
//   global_store h] [lgkm(0); barrier].  Exactly 2 barriers/step.
// ---------------------------------------------------------------------------
__global__ __launch_bounds__(512, 2) void rec_kernel(
    const float* __restrict__ Wh, const float* __restrict__ h0,
    float* __restrict__ io)
{
    __shared__ float h_s[HH];
    __shared__ float part_s[8][HH];

    const int tid  = threadIdx.x;
    const int b    = blockIdx.x;
    const int lane = tid & 63;
    const int q    = tid >> 6;   // wave id 0..7 = k-group

    const float* wp  = Wh + (size_t)(lane * 4) * HH + q * 32; // 4 col rows
    const float* iob = io + (size_t)b * HH;                   // uniform base
    unsigned vio = tid * 4;                                   // byte voffset
    unsigned hbase = (unsigned)(size_t)&h_s[0];
    unsigned pbase = (unsigned)(size_t)&part_s[0][0];
    unsigned hb = hbase + q * 128;              // h[q*32] byte addr
    unsigned hw = hbase + (tid & 255) * 4;      // h[tid] (tid<256)
    unsigned pw = pbase + q * 1024 + lane * 16; // part[q][lane*4]
    unsigned pr = pbase + (tid & 255) * 4;      // part[0][tid]
    unsigned long long msk = __ballot(tid < HH);

    if (tid < HH) h_s[tid] = h0[(size_t)b * HH + tid];
    __syncthreads();

    asm volatile(
        // ---- w prefetch: 32x dwordx4, c-major layout base 64+32c+4m ----
        "global_load_dwordx4 v[64:67],   %[wp], off\n"
        "global_load_dwordx4 v[68:71],   %[wp], off offset:16\n"
        "global_load_dwordx4 v[72:75],   %[wp], off offset:32\n"
        "global_load_dwordx4 v[76:79],   %[wp], off offset:48\n"
        "global_load_dwordx4 v[80:83],   %[wp], off offset:64\n"
        "global_load_dwordx4 v[84:87],   %[wp], off offset:80\n"
        "global_load_dwordx4 v[88:91],   %[wp], off offset:96\n"
        "global_load_dwordx4 v[92:95],   %[wp], off offset:112\n"
        "global_load_dwordx4 v[96:99],   %[wp], off offset:1024\n"
        "global_load_dwordx4 v[100:103], %[wp], off offset:1040\n"
        "global_load_dwordx4 v[104:107], %[wp], off offset:1056\n"
        "global_load_dwordx4 v[108:111], %[wp], off offset:1072\n"
        "global_load_dwordx4 v[112:115], %[wp], off offset:1088\n"
        "global_load_dwordx4 v[116:119], %[wp], off offset:1104\n"
        "global_load_dwordx4 v[120:123], %[wp], off offset:1120\n"
        "global_load_dwordx4 v[124:127], %[wp], off offset:1136\n"
        "global_load_dwordx4 v[128:131], %[wp], off offset:2048\n"
        "global_load_dwordx4 v[132:135], %[wp], off offset:2064\n"
        "global_load_dwordx4 v[136:139], %[wp], off offset:2080\n"
        "global_load_dwordx4 v[140:143], %[wp], off offset:2096\n"
        "global_load_dwordx4 v[144:147], %[wp], off offset:2112\n"
        "global_load_dwordx4 v[148:151], %[wp], off offset:2128\n"
        "global_load_dwordx4 v[152:155], %[wp], off offset:2144\n"
        "global_load_dwordx4 v[156:159], %[wp], off offset:2160\n"
        "global_load_dwordx4 v[160:163], %[wp], off offset:3072\n"
        "global_load_dwordx4 v[164:167], %[wp], off offset:3088\n"
        "global_load_dwordx4 v[168:171], %[wp], off offset:3104\n"
        "global_load_dwordx4 v[172:175], %[wp], off offset:3120\n"
        "global_load_dwordx4 v[176:179], %[wp], off offset:3136\n"
        "global_load_dwordx4 v[180:183], %[wp], off offset:3152\n"
        "global_load_dwordx4 v[184:187], %[wp], off offset:3168\n"
        "global_load_dwordx4 v[188:191], %[wp], off offset:3184\n"
        "s_waitcnt vmcnt(0)\n"
        "s_movk_i32 s82, 0x200\n"
        "LTOP_%=:\n"
        // ---- masked xi load (waves 0-3), consumed in reduce ----
        "s_and_saveexec_b64 s[80:81], %[msk]\n"
        "global_load_dword v63, %[vio], %[iob]\n"
        "s_mov_b64 exec, s[80:81]\n"
        // ---- acc init ----
        "v_mov_b32 v48, 0\n" "v_mov_b32 v49, 0\n"
        "v_mov_b32 v50, 0\n" "v_mov_b32 v51, 0\n"
        "v_mov_b32 v52, 0\n" "v_mov_b32 v53, 0\n"
        "v_mov_b32 v54, 0\n" "v_mov_b32 v55, 0\n"
        // ---- hv prefetch: 4 quads ----
        "ds_read_b128 v[32:35], %[hb]\n"
        "ds_read_b128 v[36:39], %[hb] offset:16\n"
        "ds_read_b128 v[40:43], %[hb] offset:32\n"
        "ds_read_b128 v[44:47], %[hb] offset:48\n"
        // ---- chunk 0 (w base 64+32c) ----
        "s_waitcnt lgkmcnt(3)\n"
        "v_pk_fma_f32 v[48:49], v[64:65],   v[32:33], v[48:49]\n"
        "v_pk_fma_f32 v[50:51], v[96:97],   v[32:33], v[50:51]\n"
        "v_pk_fma_f32 v[52:53], v[128:129], v[32:33], v[52:53]\n"
        "v_pk_fma_f32 v[54:55], v[160:161], v[32:33], v[54:55]\n"
        "v_pk_fma_f32 v[48:49], v[66:67],   v[34:35], v[48:49]\n"
        "v_pk_fma_f32 v[50:51], v[98:99],   v[34:35], v[50:51]\n"
        "v_pk_fma_f32 v[52:53], v[130:131], v[34:35], v[52:53]\n"
        "v_pk_fma_f32 v[54:55], v[162:163], v[34:35], v[54:55]\n"
        "ds_read_b128 v[32:35], %[hb] offset:64\n"
        // ---- chunk 1 ----
        "s_waitcnt lgkmcnt(3)\n"
        "v_pk_fma_f32 v[48:49], v[68:69],   v[36:37], v[48:49]\n"
        "v_pk_fma_f32 v[50:51], v[100:101], v[36:37], v[50:51]\n"
        "v_pk_fma_f32 v[52:53], v[132:133], v[36:37], v[52:53]\n"
        "v_pk_fma_f32 v[54:55], v[164:165], v[36:37], v[54:55]\n"
        "v_pk_fma_f32 v[48:49], v[70:71],   v[38:39], v[48:49]\n"
        "v_pk_fma_f32 v[50:51], v[102:103], v[38:39], v[50:51]\n"
        "v_pk_fma_f32 v[52:53], v[134:135], v[38:39], v[52:53]\n"
        "v_pk_fma_f32 v[54:55], v[166:167], v[38:39], v[54:55]\n"
        "ds_read_b128 v[36:39], %[hb] offset:80\n"
        // ---- chunk 2 ----
        "s_waitcnt lgkmcnt(3)\n"
        "v_pk_fma_f32 v[48:49], v[72:73],   v[40:41], v[48:49]\n"
        "v_pk_fma_f32 v[50:51], v[104:105], v[40:41], v[50:51]\n"
        "v_pk_fma_f32 v[52:53], v[136:137], v[40:41], v[52:53]\n"
        "v_pk_fma_f32 v[54:55], v[168:169], v[40:41], v[54:55]\n"
        "v_pk_fma_f32 v[48:49], v[74:75],   v[42:43], v[48:49]\n"
        "v_pk_fma_f32 v[50:51], v[106:107], v[42:43], v[50:51]\n"
        "v_pk_fma_f32 v[52:53], v[138:139], v[42:43], v[52:53]\n"
        "v_pk_fma_f32 v[54:55], v[170:171], v[42:43], v[54:55]\n"
        "ds_read_b128 v[40:43], %[hb] offset:96\n"
        // ---- chunk 3 ----
        "s_waitcnt lgkmcnt(3)\n"
        "v_pk_fma_f32 v[48:49], v[76:77],   v[44:45], v[48:49]\n"
        "v_pk_fma_f32 v[50:51], v[108:109], v[44:45], v[50:51]\n"
        "v_pk_fma_f32 v[52:53], v[140:141], v[44:45], v[52:53]\n"
        "v_pk_fma_f32 v[54:55], v[172:173], v[44:45], v[54:55]\n"
        "v_pk_fma_f32 v[48:49], v[78:79],   v[46:47], v[48:49]\n"
        "v_pk_fma_f32 v[50:51], v[110:111], v[46:47], v[50:51]\n"
        "v_pk_fma_f32 v[52:53], v[142:143], v[46:47], v[52:53]\n"
        "v_pk_fma_f32 v[54:55], v[174:175], v[46:47], v[54:55]\n"
        "ds_read_b128 v[44:47], %[hb] offset:112\n"
        // ---- chunk 4 ----
        "s_waitcnt lgkmcnt(3)\n"
        "v_pk_fma_f32 v[48:49], v[80:81],   v[32:33], v[48:49]\n"
        "v_pk_fma_f32 v[50:51], v[112:113], v[32:33], v[50:51]\n"
        "v_pk_fma_f32 v[52:53], v[144:145], v[32:33], v[52:53]\n"
        "v_pk_fma_f32 v[54:55], v[176:177], v[32:33], v[54:55]\n"
        "v_pk_fma_f32 v[48:49], v[82:83],   v[34:35], v[48:49]\n"
        "v_pk_fma_f32 v[50:51], v[114:115], v[34:35], v[50:51]\n"
        "v_pk_fma_f32 v[52:53], v[146:147], v[34:35], v[52:53]\n"
        "v_pk_fma_f32 v[54:55], v[178:179], v[34:35], v[54:55]\n"
        // ---- chunk 5 ----
        "s_waitcnt lgkmcnt(2)\n"
        "v_pk_fma_f32 v[48:49], v[84:85],   v[36:37], v[48:49]\n"
        "v_pk_fma_f32 v[50:51], v[116:117], v[36:37], v[50:51]\n"
        "v_pk_fma_f32 v[52:53], v[148:149], v[36:37], v[52:53]\n"
        "v_pk_fma_f32 v[54:55], v[180:181], v[36:37], v[54:55]\n"
        "v_pk_fma_f32 v[48:49], v[86:87],   v[38:39], v[48:49]\n"
        "v_pk_fma_f32 v[50:51], v[118:119], v[38:39], v[50:51]\n"
        "v_pk_fma_f32 v[52:53], v[150:151], v[38:39], v[52:53]\n"
        "v_pk_fma_f32 v[54:55], v[182:183], v[38:39], v[54:55]\n"
        // ---- chunk 6 ----
        "s_waitcnt lgkmcnt(1)\n"
        "v_pk_fma_f32 v[48:49], v[88:89],   v[40:41], v[48:49]\n"
        "v_pk_fma_f32 v[50:51], v[120:121], v[40:41], v[50:51]\n"
        "v_pk_fma_f32 v[52:53], v[152:153], v[40:41], v[52:53]\n"
        "v_pk_fma_f32 v[54:55], v[184:185], v[40:41], v[54:55]\n"
        "v_pk_fma_f32 v[48:49], v[90:91],   v[42:43], v[48:49]\n"
        "v_pk_fma_f32 v[50:51], v[122:123], v[42:43], v[50:51]\n"
        "v_pk_fma_f32 v[52:53], v[154:155], v[42:43], v[52:53]\n"
        "v_pk_fma_f32 v[54:55], v[186:187], v[42:43], v[54:55]\n"
        // ---- chunk 7 ----
        "s_waitcnt lgkmcnt(0)\n"
        "v_pk_fma_f32 v[48:49], v[92:93],   v[44:45], v[48:49]\n"
        "v_pk_fma_f32 v[50:51], v[124:125], v[44:45], v[50:51]\n"
        "v_pk_fma_f32 v[52:53], v[156:157], v[44:45], v[52:53]\n"
        "v_pk_fma_f32 v[54:55], v[188:189], v[44:45], v[54:55]\n"
        "v_pk_fma_f32 v[48:49], v[94:95],   v[46:47], v[48:49]\n"
        "v_pk_fma_f32 v[50:51], v[126:127], v[46:47], v[50:51]\n"
        "v_pk_fma_f32 v[52:53], v[158:159], v[46:47], v[52:53]\n"
        "v_pk_fma_f32 v[54:55], v[190:191], v[46:47], v[54:55]\n"
        // ---- merge pairs, write 4 partials (b128) ----
        "v_add_f32 v56, v48, v49\n"
        "v_add_f32 v57, v50, v51\n"
        "v_add_f32 v58, v52, v53\n"
        "v_add_f32 v59, v54, v55\n"
        "ds_write_b128 %[pw], v[56:59]\n"
        "s_waitcnt lgkmcnt(0)\n"
        "s_barrier\n"
        // ---- reduce (waves 0-3): 8 partials + xi, tanh, store ----
        "s_and_saveexec_b64 s[80:81], %[msk]\n"
        "ds_read_b32 v32, %[pr]\n"
        "ds_read_b32 v33, %[pr] offset:1024\n"
        "ds_read_b32 v34, %[pr] offset:2048\n"
        "ds_read_b32 v35, %[pr] offset:3072\n"
        "ds_read_b32 v36, %[pr] offset:4096\n"
        "ds_read_b32 v37, %[pr] offset:5120\n"
        "ds_read_b32 v38, %[pr] offset:6144\n"
        "ds_read_b32 v39, %[pr] offset:7168\n"
        "s_waitcnt vmcnt(0) lgkmcnt(0)\n"
        "v_add_f32 v32, v32, v33\n"
        "v_add_f32 v34, v34, v35\n"
        "v_add_f32 v36, v36, v37\n"
        "v_add_f32 v38, v38, v39\n"
        "v_add_f32 v32, v32, v34\n"
        "v_add_f32 v36, v36, v38\n"
        "v_add_f32 v32, v32, v36\n"
        "v_add_f32 v32, v32, v63\n"          // + xi
        "v_mul_f32 v33, 0x4038aa3b, v32\n"   // t * 2*log2(e)
        "v_exp_f32 v33, v33\n"
        "s_nop 1\n"
        "v_add_f32 v33, 1.0, v33\n"
        "v_rcp_f32 v33, v33\n"
        "s_nop 1\n"
        "v_fma_f32 v32, -2.0, v33, 1.0\n"    // hn = 1 - 2/(e+1)
        "ds_write_b32 %[hw], v32\n"
        "global_store_dword %[vio], v32, %[iob]\n"
        "s_mov_b64 exec, s[80:81]\n"
        "s_waitcnt lgkmcnt(0)\n"
        "s_barrier\n"
        // ---- bookkeeping ----
        "v_add_u32 %[vio], 0x40000, %[vio]\n"
        "s_sub_u32 s82, s82, 1\n"
        "s_cmp_lg_u32 s82, 0\n"
        "s_cbranch_scc1 LTOP_%=\n"
        : [vio] "+v"(vio)
        : [wp] "v"(wp), [iob] "s"(iob), [msk] "s"(msk),
          [hb] "v"(hb), [hw] "v"(hw), [pw] "v"(pw), [pr] "v"(pr)
        : "memory", "scc", "s80", "s81", "s82",
          "v32","v33","v34","v35","v36","v37","v38","v39",
          "v40","v41","v42","v43","v44","v45","v46","v47",
          "v48","v49","v50","v51","v52","v53","v54","v55",
          "v56","v57","v58","v59","v60","v61","v62","v63",
          "v64","v65","v66","v67","v68","v69","v70","v71",
          "v72","v73","v74","v75","v76","v77","v78","v79",
          "v80","v81","v82","v83","v84","v85","v86","v87",
          "v88","v89","v90","v91","v92","v93","v94","v95",
          "v96","v97","v98","v99","v100","v101","v102","v103",
          "v104","v105","v106","v107","v108","v109","v110","v111",
          "v112","v113","v114","v115","v116","v117","v118","v119",
          "v120","v121","v122","v123","v124","v125","v126","v127",
          "v128","v129","v130","v131","v132","v133","v134","v135",
          "v136","v137","v138","v139","v140","v141","v142","v143",
          "v144","v145","v146","v147","v148","v149","v150","v151",
          "v152","v153","v154","v155","v156","v157","v158","v159",
          "v160","v161","v162","v163","v164","v165","v166","v167",
          "v168","v169","v170","v171","v172","v173","v174","v175",
          "v176","v177","v178","v179","v180","v181","v182","v183",
          "v184","v185","v186","v187","v188","v189","v190","v191");
}

extern "C" void kernel_launch(void* const* d_in, const int* in_sizes, int n_in,
                              void* d_out, int out_size, void* d_ws, size_t ws_size,
                              hipStream_t stream) {
    const float* x  = (const float*)d_in[0];  // [T,B,I]
    const float* h0 = (const float*)d_in[1];  // [B,H]
    const float* Wi = (const float*)d_in[2];  // [H,I]
    const float* Wh = (const float*)d_in[3];  // [H,H]
    const float* bh = (const float*)d_in[4];  // [H]
    float* out = (float*)d_out;               // [T,B,H]

    dim3 pgrid(TT * BB / 64, HH / 64);
    proj_kernel<<<pgrid, 256, 0, stream>>>(x, Wi, bh, out);
    rec_kernel<<<BB, 512, 0, stream>>>(Wh, h0, out);
}